// Round 12
// baseline (570.783 us; speedup 1.0000x reference)
//
#include <hip/hip_runtime.h>
#include <hip/hip_bf16.h>

typedef short bf16x8 __attribute__((ext_vector_type(8)));
typedef float f32x4  __attribute__((ext_vector_type(4)));
typedef unsigned short ushort_t;

#define DT_F     0.1f
#define LN_EPS_F 1e-3f

__device__ __forceinline__ ushort_t f2bf(float v) {
    union { float f; unsigned u; } x; x.f = v;
    unsigned r = x.u + 0x7fffu + ((x.u >> 16) & 1u);   // round-to-nearest-even
    return (ushort_t)(r >> 16);
}
// packed RNE f32x2 -> bf16x2 in one VALU op
__device__ __forceinline__ unsigned pk2(float a, float b) {
    unsigned r;
    asm("v_cvt_pk_bf16_f32 %0, %1, %2" : "=v"(r) : "v"(a), "v"(b));
    return r;
}

// ---------------------------------------------------------------------------
// Pack W1 (128x512) and W2 (512x128) into MFMA A-fragment order (swapped GEMM:
// A = W^T), single bf16, k-permutation pi(ks,g,j)=16*(2ks+(j>>2))+4g+(j&3).
// W1pack: [mh 32][ku 4][lane 64][8]   W2pack: [mu2 8][kh 16][lane 64][8]
// ---------------------------------------------------------------------------
__global__ __launch_bounds__(256)
void pack_weights(const float* __restrict__ W1, const float* __restrict__ W2,
                  ushort_t* __restrict__ w1p, ushort_t* __restrict__ w2p)
{
    int tid  = blockIdx.x * 256 + threadIdx.x;   // 0..16383
    int lane = tid & 63;
    int g = lane >> 4, l15 = lane & 15;
    int fi = tid >> 6;                            // 0..255
    bf16x8 hi;
    if (fi < 128) {
        int mh = fi >> 2, ku = fi & 3;
        #pragma unroll
        for (int j = 0; j < 8; ++j) {
            int u = 16 * (2 * ku + (j >> 2)) + 4 * g + (j & 3);
            hi[j] = (short)f2bf(W1[u * 512 + 16 * mh + l15]);
        }
        ((bf16x8*)w1p)[fi * 64 + lane] = hi;
    } else {
        int fj = fi - 128;
        int mu2 = fj >> 4, kh = fj & 15;
        #pragma unroll
        for (int j = 0; j < 8; ++j) {
            int hr = 16 * (2 * kh + (j >> 2)) + 4 * g + (j & 3);
            hi[j] = (short)f2bf(W2[hr * 128 + 16 * mu2 + l15]);
        }
        ((bf16x8*)w2p)[fj * 64 + lane] = hi;
    }
}

// ---------------------------------------------------------------------------
// Persistent ODE kernel: 512 blocks x 512 threads (8 waves); block owns 32 rows.
// Weights, biases, gamma/beta all pinned in registers (loaded once) ->
// ZERO global loads and minimal LDS traffic inside the 81-eval loop.
// launch_bounds(512,2) -> 256-VGPR cap, 2 waves/SIMD, 1 block/CU resident.
// Wave w: mm1 computes mh = 4w..4w+3 for both nb; writes kh = 2w..2w+1;
//         mm2 computes mu2 = w (u-cols 16w..16w+15) for both nb.
// ---------------------------------------------------------------------------
__global__ __launch_bounds__(512, 2)
void node_ode(const float* __restrict__ x0,
              const float* __restrict__ gamma, const float* __restrict__ beta,
              const float* __restrict__ b1,    const float* __restrict__ b2,
              const ushort_t* __restrict__ w1p, const ushort_t* __restrict__ w2p,
              float* __restrict__ out, float* __restrict__ regPart)
{
    extern __shared__ char smem[];
    ushort_t* xinh = (ushort_t*)smem;              // [2nb][4ku][2half][64][4]   8 KB
    ushort_t* hbuf = (ushort_t*)(smem + 8192);     // [16kh][2nb][64][8]        32 KB
    float*    gbuf = (float*)(smem + 40960);       // [512][{gamma,beta}]        4 KB (staging; dead after pin)
    float*    b1b  = (float*)(smem + 45056);       // 2 KB (staging)
    float*    b2b  = (float*)(smem + 47104);       // 512 B (staging)
    float2*   lnb  = (float2*)(smem + 47616);      // [8w][2nb][16] float2       2 KB
    float*    rmx  = (float*)(smem + 49664);       // [8w][2nb][16]              1 KB
    // total 50688 B

    const int t = threadIdx.x, lane = t & 63, w = t >> 6;
    const int g = lane >> 4, l15 = lane & 15;
    const int row0 = blockIdx.x * 32;

    const bf16x8* w1v = (const bf16x8*)w1p;
    const bf16x8* w2v = (const bf16x8*)w2p;

    gbuf[2 * t] = gamma[t]; gbuf[2 * t + 1] = beta[t]; b1b[t] = b1[t];
    if (t < 128) b2b[t] = b2[t];

    // Pinned weights:
    // W1r: mh = 4w+mhi, ku          (16 frags = 64 VGPR)
    // W2r: mu2 = w, kh              (16 frags = 64 VGPR)
    bf16x8 W1r[4][4], W2r[16];
    #pragma unroll
    for (int mhi = 0; mhi < 4; ++mhi)
        #pragma unroll
        for (int ku = 0; ku < 4; ++ku)
            W1r[mhi][ku] = w1v[((4 * w + mhi) * 4 + ku) * 64 + lane];
    #pragma unroll
    for (int kh = 0; kh < 16; ++kh)
        W2r[kh] = w2v[(w * 16 + kh) * 64 + lane];

    // x state: xreg[nb] = rows 16nb+l15, ucols 16w+4g..+3
    f32x4 xreg[2], acck[2], kreg[2];
    #pragma unroll
    for (int nb = 0; nb < 2; ++nb) {
        int brow = row0 + 16 * nb + l15;
        int ucol = 16 * w + 4 * g;
        xreg[nb] = *(const f32x4*)&x0[brow * 128 + ucol];
        kreg[nb] = (f32x4)0.0f;
    }
    __syncthreads();

    // Pin biases + gamma/beta pairs (loop-invariant per-eval LDS reads -> regs)
    f32x4 b1f[4];
    #pragma unroll
    for (int mhi = 0; mhi < 4; ++mhi)
        b1f[mhi] = *(const f32x4*)&b1b[16 * (4 * w + mhi) + 4 * g];
    f32x4 b2f = *(const f32x4*)&b2b[16 * w + 4 * g];
    float2 GPr[2][2][4];
    #pragma unroll
    for (int khl = 0; khl < 2; ++khl)
        #pragma unroll
        for (int half = 0; half < 2; ++half) {
            int mh = 4 * w + 2 * khl + half;
            #pragma unroll
            for (int r = 0; r < 4; ++r)
                GPr[khl][half][r] = *(const float2*)&gbuf[(16 * mh + 4 * g + r) * 2];
        }

    float regtot = 0.0f;

    // xin: [nb][ku][half][64][4]; wave w supplies (ku=w>>1, half=w&1):
    // one contiguous 8B write per nb (2-way bank alias = free).
    auto build_xin = [&](float c) {
        #pragma unroll
        for (int nb = 0; nb < 2; ++nb) {
            f32x4 xv = xreg[nb];
            if (c != 0.0f) xv += kreg[nb] * c;
            unsigned h01 = pk2(xv[0], xv[1]);
            unsigned h23 = pk2(xv[2], xv[3]);
            int off = (((nb * 4 + (w >> 1)) * 2 + (w & 1)) * 64 + lane) * 4;
            *reinterpret_cast<uint2*>(&xinh[off]) = make_uint2(h01, h23);
        }
    };

    // mm1 (C1^T = W1^T x^T) + LayerNorm + ReLU -> hbuf (bf16); weights+consts from regs
    auto do_mm1_ln = [&]() {
        f32x4 acc[4][2];
        #pragma unroll
        for (int mhi = 0; mhi < 4; ++mhi)
            #pragma unroll
            for (int nb = 0; nb < 2; ++nb) acc[mhi][nb] = b1f[mhi];
        #pragma unroll
        for (int ku = 0; ku < 4; ++ku) {
            bf16x8 Bh[2];
            #pragma unroll
            for (int nb = 0; nb < 2; ++nb) {
                int base = (((nb * 4 + ku) * 2) * 64 + lane) * 4;
                union { uint2 u2[2]; bf16x8 v; } uu;
                uu.u2[0] = *reinterpret_cast<const uint2*>(&xinh[base]);        // half 0
                uu.u2[1] = *reinterpret_cast<const uint2*>(&xinh[base + 256]);  // half 1
                Bh[nb] = uu.v;
            }
            #pragma unroll
            for (int mhi = 0; mhi < 4; ++mhi) {
                #pragma unroll
                for (int nb = 0; nb < 2; ++nb)
                    acc[mhi][nb] = __builtin_amdgcn_mfma_f32_16x16x32_bf16(W1r[mhi][ku], Bh[nb], acc[mhi][nb], 0, 0, 0);
            }
        }
        // LayerNorm stats: this wave holds 64 of 512 cols for rows 16nb+l15
        float s1[2] = {0,0}, s2[2] = {0,0};
        #pragma unroll
        for (int nb = 0; nb < 2; ++nb)
            #pragma unroll
            for (int mhi = 0; mhi < 4; ++mhi)
                #pragma unroll
                for (int r = 0; r < 4; ++r) {
                    float v = acc[mhi][nb][r];
                    s1[nb] += v; s2[nb] = fmaf(v, v, s2[nb]);
                }
        #pragma unroll
        for (int nb = 0; nb < 2; ++nb) {
            s1[nb] += __shfl_xor(s1[nb], 16); s1[nb] += __shfl_xor(s1[nb], 32);
            s2[nb] += __shfl_xor(s2[nb], 16); s2[nb] += __shfl_xor(s2[nb], 32);
        }
        if (lane < 16) {
            #pragma unroll
            for (int nb = 0; nb < 2; ++nb)
                lnb[(w * 2 + nb) * 16 + l15] = make_float2(s1[nb], s2[nb]);
        }
        __syncthreads();
        float mu_[2], rs_[2];
        #pragma unroll
        for (int nb = 0; nb < 2; ++nb) {
            float t1 = 0.f, t2 = 0.f;
            #pragma unroll
            for (int ww = 0; ww < 8; ++ww) {
                float2 v = lnb[(ww * 2 + nb) * 16 + l15];
                t1 += v.x; t2 += v.y;
            }
            float m = t1 * (1.0f / 512.0f);
            float var = t2 * (1.0f / 512.0f) - m * m;
            mu_[nb] = m; rs_[nb] = rsqrtf(var + LN_EPS_F);
        }
        // apply LN * gamma + beta, ReLU, bf16 -> hbuf; one b128 write per (kh,nb)
        #pragma unroll
        for (int khl = 0; khl < 2; ++khl) {
            #pragma unroll
            for (int nb = 0; nb < 2; ++nb) {
                float v[8];
                #pragma unroll
                for (int half = 0; half < 2; ++half) {
                    int mhi = 2 * khl + half;
                    #pragma unroll
                    for (int r = 0; r < 4; ++r)
                        v[half * 4 + r] = fmaxf(fmaf((acc[mhi][nb][r] - mu_[nb]) * rs_[nb],
                                                     GPr[khl][half][r].x, GPr[khl][half][r].y), 0.f);
                }
                uint4 q;
                q.x = pk2(v[0], v[1]); q.y = pk2(v[2], v[3]);
                q.z = pk2(v[4], v[5]); q.w = pk2(v[6], v[7]);
                int kh = 2 * w + khl;
                *reinterpret_cast<uint4*>(&hbuf[((kh * 2 + nb) * 64 + lane) * 8]) = q;
            }
        }
    };

    // mm2 (out^T = W2^T h^T) -> kreg ; weights+bias from regs
    auto do_mm2 = [&]() {
        #pragma unroll
        for (int nb = 0; nb < 2; ++nb) kreg[nb] = b2f;
        #pragma unroll
        for (int kh = 0; kh < 16; ++kh) {
            bf16x8 Bf[2];
            #pragma unroll
            for (int nb = 0; nb < 2; ++nb)
                Bf[nb] = *(const bf16x8*)&hbuf[((kh * 2 + nb) * 64 + lane) * 8];
            #pragma unroll
            for (int nb = 0; nb < 2; ++nb)
                kreg[nb] = __builtin_amdgcn_mfma_f32_16x16x32_bf16(W2r[kh], Bf[nb], kreg[nb], 0, 0, 0);
        }
    };

    auto f_eval = [&](float c) {
        build_xin(c);
        __syncthreads();
        do_mm1_ln();
        __syncthreads();
        do_mm2();
    };

    // regularization from kreg (= f(x) at current state)
    auto do_reg = [&]() {
        float amax[2] = {0, 0};
        #pragma unroll
        for (int nb = 0; nb < 2; ++nb)
            #pragma unroll
            for (int r = 0; r < 4; ++r)
                amax[nb] = fmaxf(amax[nb], fabsf(kreg[nb][r]));
        #pragma unroll
        for (int nb = 0; nb < 2; ++nb) {
            amax[nb] = fmaxf(amax[nb], __shfl_xor(amax[nb], 16));
            amax[nb] = fmaxf(amax[nb], __shfl_xor(amax[nb], 32));
        }
        if (lane < 16) {
            #pragma unroll
            for (int nb = 0; nb < 2; ++nb) rmx[(w * 2 + nb) * 16 + l15] = amax[nb];
        }
        __syncthreads();
        float rmax_[2];
        #pragma unroll
        for (int nb = 0; nb < 2; ++nb) {
            float m = rmx[(0 * 2 + nb) * 16 + l15];
            #pragma unroll
            for (int ww = 1; ww < 8; ++ww) m = fmaxf(m, rmx[(ww * 2 + nb) * 16 + l15]);
            rmax_[nb] = m;
        }
        float se[2] = {0, 0}, sa[2] = {0, 0};
        #pragma unroll
        for (int nb = 0; nb < 2; ++nb)
            #pragma unroll
            for (int r = 0; r < 4; ++r) {
                float a = fabsf(kreg[nb][r]);
                float e = __expf(a - rmax_[nb]);
                se[nb] += e; sa[nb] = fmaf(a, e, sa[nb]);
            }
        #pragma unroll
        for (int nb = 0; nb < 2; ++nb) {
            se[nb] += __shfl_xor(se[nb], 16); se[nb] += __shfl_xor(se[nb], 32);
            sa[nb] += __shfl_xor(sa[nb], 16); sa[nb] += __shfl_xor(sa[nb], 32);
        }
        if (lane < 16) {
            #pragma unroll
            for (int nb = 0; nb < 2; ++nb)
                lnb[(w * 2 + nb) * 16 + l15] = make_float2(se[nb], sa[nb]);
        }
        __syncthreads();
        if (w == 0) {
            // lanes 0..31 cover rows 16*(g&1)+l15
            int nb = g & 1;
            float nse = 0.f, nsa = 0.f;
            #pragma unroll
            for (int ww = 0; ww < 8; ++ww) {
                float2 v = lnb[(ww * 2 + nb) * 16 + l15];
                nse += v.x; nsa += v.y;
            }
            float nrm = (lane < 32) ? (nsa / nse) : 0.0f;
            #pragma unroll
            for (int m = 1; m < 64; m <<= 1) nrm += __shfl_xor(nrm, m);
            if (lane == 0) regtot += nrm;
        }
        __syncthreads();
    };

    for (int s = 0; s < 20; ++s) {
        f_eval(0.0f);                                   // k1 = f(x_s)
        if (s >= 12 && (s & 1) == 0) do_reg();          // x_s is reg state for s=12,14,16,18
        #pragma unroll
        for (int nb = 0; nb < 2; ++nb) acck[nb] = kreg[nb];
        f_eval(0.5f * DT_F);
        #pragma unroll
        for (int nb = 0; nb < 2; ++nb) acck[nb] += kreg[nb] * 2.0f;
        f_eval(0.5f * DT_F);
        #pragma unroll
        for (int nb = 0; nb < 2; ++nb) acck[nb] += kreg[nb] * 2.0f;
        f_eval(DT_F);
        #pragma unroll
        for (int nb = 0; nb < 2; ++nb) {
            acck[nb] += kreg[nb];
            xreg[nb] += acck[nb] * (DT_F / 6.0f);
        }
    }
    // final regularization eval at x_20
    f_eval(0.0f);
    do_reg();

    #pragma unroll
    for (int nb = 0; nb < 2; ++nb) {
        int brow = row0 + 16 * nb + l15;
        int ucol = 16 * w + 4 * g;
        *(f32x4*)&out[brow * 128 + ucol] = xreg[nb];
    }
    if (t == 0) regPart[blockIdx.x] = regtot;
}

__global__ __launch_bounds__(64)
void finalize_reg(const float* __restrict__ regPart, float* __restrict__ outReg)
{
    int t = threadIdx.x;
    float s = 0.f;
    #pragma unroll
    for (int i = 0; i < 8; ++i) s += regPart[t + 64 * i];
    #pragma unroll
    for (int m = 1; m < 64; m <<= 1) s += __shfl_xor(s, m);
    if (t == 0) outReg[0] = s * (1.0f / (5.0f * 16384.0f));
}

extern "C" void kernel_launch(void* const* d_in, const int* in_sizes, int n_in,
                              void* d_out, int out_size, void* d_ws, size_t ws_size,
                              hipStream_t stream)
{
    (void)in_sizes; (void)n_in; (void)out_size; (void)ws_size;
    const float* x0    = (const float*)d_in[0];
    const float* W1    = (const float*)d_in[1];
    const float* b1    = (const float*)d_in[2];
    const float* gamma = (const float*)d_in[3];
    const float* beta  = (const float*)d_in[4];
    const float* W2    = (const float*)d_in[5];
    const float* b2    = (const float*)d_in[6];
    float* out = (float*)d_out;

    ushort_t* w1p = (ushort_t*)d_ws;                       // 128 KB
    ushort_t* w2p = w1p + 65536;                           // 128 KB
    float* regPart = (float*)((char*)d_ws + 262144);       // 2 KB

    pack_weights<<<64, 256, 0, stream>>>(W1, W2, w1p, w2p);
    node_ode<<<512, 512, 50688, stream>>>(x0, gamma, beta, b1, b2, w1p, w2p, out, regPart);
    finalize_reg<<<1, 64, 0, stream>>>(regPart, out + 2097152);
}

// Round 13
// 416.005 us; speedup vs baseline: 1.3721x; 1.3721x over previous
//
#include <hip/hip_runtime.h>
#include <hip/hip_bf16.h>

typedef short bf16x8 __attribute__((ext_vector_type(8)));
typedef float f32x4  __attribute__((ext_vector_type(4)));
typedef unsigned short ushort_t;

#define DT_F     0.1f
#define LN_EPS_F 1e-3f

__device__ __forceinline__ ushort_t f2bf(float v) {
    union { float f; unsigned u; } x; x.f = v;
    unsigned r = x.u + 0x7fffu + ((x.u >> 16) & 1u);   // round-to-nearest-even
    return (ushort_t)(r >> 16);
}
// packed RNE f32x2 -> bf16x2 in one VALU op
__device__ __forceinline__ unsigned pk2(float a, float b) {
    unsigned r;
    asm("v_cvt_pk_bf16_f32 %0, %1, %2" : "=v"(r) : "v"(a), "v"(b));
    return r;
}

// ---------------------------------------------------------------------------
// Pack W1 (128x512) and W2 (512x128) into MFMA A-fragment order (swapped GEMM:
// A = W^T), single bf16, k-permutation pi(ks,g,j)=16*(2ks+(j>>2))+4g+(j&3).
// W1pack: [mh 32][ku 4][lane 64][8]   W2pack: [mu2 8][kh 16][lane 64][8]
// ---------------------------------------------------------------------------
__global__ __launch_bounds__(256)
void pack_weights(const float* __restrict__ W1, const float* __restrict__ W2,
                  ushort_t* __restrict__ w1p, ushort_t* __restrict__ w2p)
{
    int tid  = blockIdx.x * 256 + threadIdx.x;   // 0..16383
    int lane = tid & 63;
    int g = lane >> 4, l15 = lane & 15;
    int fi = tid >> 6;                            // 0..255
    bf16x8 hi;
    if (fi < 128) {
        int mh = fi >> 2, ku = fi & 3;
        #pragma unroll
        for (int j = 0; j < 8; ++j) {
            int u = 16 * (2 * ku + (j >> 2)) + 4 * g + (j & 3);
            hi[j] = (short)f2bf(W1[u * 512 + 16 * mh + l15]);
        }
        ((bf16x8*)w1p)[fi * 64 + lane] = hi;
    } else {
        int fj = fi - 128;
        int mu2 = fj >> 4, kh = fj & 15;
        #pragma unroll
        for (int j = 0; j < 8; ++j) {
            int hr = 16 * (2 * kh + (j >> 2)) + 4 * g + (j & 3);
            hi[j] = (short)f2bf(W2[hr * 128 + 16 * mu2 + l15]);
        }
        ((bf16x8*)w2p)[fj * 64 + lane] = hi;
    }
}

// ---------------------------------------------------------------------------
// Persistent ODE kernel: 512 blocks x 512 threads (8 waves); block owns 32 rows.
// Weight fragments pinned in registers (W1 16 + W2 16 frags/wave, loaded once)
// -> zero global loads inside the 81-eval loop. launch_bounds(512,2) -> 256
// VGPR cap, 2 waves/SIMD, 1 block/CU. LN/reg exchange via float2 b64 LDS ops.
// Wave w: mm1 computes mh = 4w..4w+3 for both nb; writes kh = 2w..2w+1;
//         mm2 computes mu2 = w (u-cols 16w..16w+15) for both nb.
// ---------------------------------------------------------------------------
__global__ __launch_bounds__(512, 2)
void node_ode(const float* __restrict__ x0,
              const float* __restrict__ gamma, const float* __restrict__ beta,
              const float* __restrict__ b1,    const float* __restrict__ b2,
              const ushort_t* __restrict__ w1p, const ushort_t* __restrict__ w2p,
              float* __restrict__ out, float* __restrict__ regPart)
{
    extern __shared__ char smem[];
    ushort_t* xinh = (ushort_t*)smem;              // [2nb][4ku][2half][64][4]   8 KB
    ushort_t* hbuf = (ushort_t*)(smem + 8192);     // [16kh][2nb][64][8]        32 KB
    float*    gbuf = (float*)(smem + 40960);       // [512][{gamma,beta}]        4 KB
    float*    b1b  = (float*)(smem + 45056);       // 2 KB
    float*    b2b  = (float*)(smem + 47104);       // 512 B
    float2*   lnb  = (float2*)(smem + 47616);      // [8w][2nb][16] float2       2 KB
    float*    rmx  = (float*)(smem + 49664);       // [8w][2nb][16]              1 KB
    // total 50688 B

    const int t = threadIdx.x, lane = t & 63, w = t >> 6;
    const int g = lane >> 4, l15 = lane & 15;
    const int row0 = blockIdx.x * 32;

    const bf16x8* w1v = (const bf16x8*)w1p;
    const bf16x8* w2v = (const bf16x8*)w2p;

    gbuf[2 * t] = gamma[t]; gbuf[2 * t + 1] = beta[t]; b1b[t] = b1[t];
    if (t < 128) b2b[t] = b2[t];

    // Pinned weights:
    // W1r: mh = 4w+mhi, ku          (16 frags = 64 VGPR)
    // W2r: mu2 = w, kh              (16 frags = 64 VGPR)
    bf16x8 W1r[4][4], W2r[16];
    #pragma unroll
    for (int mhi = 0; mhi < 4; ++mhi)
        #pragma unroll
        for (int ku = 0; ku < 4; ++ku)
            W1r[mhi][ku] = w1v[((4 * w + mhi) * 4 + ku) * 64 + lane];
    #pragma unroll
    for (int kh = 0; kh < 16; ++kh)
        W2r[kh] = w2v[(w * 16 + kh) * 64 + lane];

    // x state: xreg[nb] = rows 16nb+l15, ucols 16w+4g..+3
    f32x4 xreg[2], acck[2], kreg[2];
    #pragma unroll
    for (int nb = 0; nb < 2; ++nb) {
        int brow = row0 + 16 * nb + l15;
        int ucol = 16 * w + 4 * g;
        xreg[nb] = *(const f32x4*)&x0[brow * 128 + ucol];
        kreg[nb] = (f32x4)0.0f;
    }
    __syncthreads();

    float regtot = 0.0f;

    // xin: [nb][ku][half][64][4]; wave w supplies (ku=w>>1, half=w&1):
    // one contiguous 8B write per nb (2-way bank alias = free).
    auto build_xin = [&](float c) {
        #pragma unroll
        for (int nb = 0; nb < 2; ++nb) {
            f32x4 xv = xreg[nb];
            if (c != 0.0f) xv += kreg[nb] * c;
            unsigned h01 = pk2(xv[0], xv[1]);
            unsigned h23 = pk2(xv[2], xv[3]);
            int off = (((nb * 4 + (w >> 1)) * 2 + (w & 1)) * 64 + lane) * 4;
            *reinterpret_cast<uint2*>(&xinh[off]) = make_uint2(h01, h23);
        }
    };

    // mm1 (C1^T = W1^T x^T) + LayerNorm + ReLU -> hbuf (bf16); weights from regs
    auto do_mm1_ln = [&]() {
        f32x4 acc[4][2];
        #pragma unroll
        for (int mhi = 0; mhi < 4; ++mhi) {
            int mh = 4 * w + mhi;
            f32x4 bv = *(const f32x4*)&b1b[16 * mh + 4 * g];
            #pragma unroll
            for (int nb = 0; nb < 2; ++nb) acc[mhi][nb] = bv;
        }
        #pragma unroll
        for (int ku = 0; ku < 4; ++ku) {
            bf16x8 Bh[2];
            #pragma unroll
            for (int nb = 0; nb < 2; ++nb) {
                int base = (((nb * 4 + ku) * 2) * 64 + lane) * 4;
                union { uint2 u2[2]; bf16x8 v; } uu;
                uu.u2[0] = *reinterpret_cast<const uint2*>(&xinh[base]);        // half 0
                uu.u2[1] = *reinterpret_cast<const uint2*>(&xinh[base + 256]);  // half 1
                Bh[nb] = uu.v;
            }
            #pragma unroll
            for (int mhi = 0; mhi < 4; ++mhi) {
                #pragma unroll
                for (int nb = 0; nb < 2; ++nb)
                    acc[mhi][nb] = __builtin_amdgcn_mfma_f32_16x16x32_bf16(W1r[mhi][ku], Bh[nb], acc[mhi][nb], 0, 0, 0);
            }
        }
        // LayerNorm stats: this wave holds 64 of 512 cols for rows 16nb+l15
        float s1[2] = {0,0}, s2[2] = {0,0};
        #pragma unroll
        for (int nb = 0; nb < 2; ++nb)
            #pragma unroll
            for (int mhi = 0; mhi < 4; ++mhi)
                #pragma unroll
                for (int r = 0; r < 4; ++r) {
                    float v = acc[mhi][nb][r];
                    s1[nb] += v; s2[nb] = fmaf(v, v, s2[nb]);
                }
        #pragma unroll
        for (int nb = 0; nb < 2; ++nb) {
            s1[nb] += __shfl_xor(s1[nb], 16); s1[nb] += __shfl_xor(s1[nb], 32);
            s2[nb] += __shfl_xor(s2[nb], 16); s2[nb] += __shfl_xor(s2[nb], 32);
        }
        if (lane < 16) {
            #pragma unroll
            for (int nb = 0; nb < 2; ++nb)
                lnb[(w * 2 + nb) * 16 + l15] = make_float2(s1[nb], s2[nb]);
        }
        __syncthreads();
        float mu_[2], rs_[2];
        #pragma unroll
        for (int nb = 0; nb < 2; ++nb) {
            float t1 = 0.f, t2 = 0.f;
            #pragma unroll
            for (int ww = 0; ww < 8; ++ww) {
                float2 v = lnb[(ww * 2 + nb) * 16 + l15];
                t1 += v.x; t2 += v.y;
            }
            float m = t1 * (1.0f / 512.0f);
            float var = t2 * (1.0f / 512.0f) - m * m;
            mu_[nb] = m; rs_[nb] = rsqrtf(var + LN_EPS_F);
        }
        // apply LN * gamma + beta, ReLU, bf16 -> hbuf; one b128 write per (kh,nb)
        #pragma unroll
        for (int khl = 0; khl < 2; ++khl) {
            float2 gp[2][4];
            #pragma unroll
            for (int half = 0; half < 2; ++half) {
                int mh = 4 * w + 2 * khl + half;
                #pragma unroll
                for (int r = 0; r < 4; ++r)
                    gp[half][r] = *(const float2*)&gbuf[(16 * mh + 4 * g + r) * 2];
            }
            #pragma unroll
            for (int nb = 0; nb < 2; ++nb) {
                float v[8];
                #pragma unroll
                for (int half = 0; half < 2; ++half) {
                    int mhi = 2 * khl + half;
                    #pragma unroll
                    for (int r = 0; r < 4; ++r)
                        v[half * 4 + r] = fmaxf(fmaf((acc[mhi][nb][r] - mu_[nb]) * rs_[nb],
                                                     gp[half][r].x, gp[half][r].y), 0.f);
                }
                uint4 q;
                q.x = pk2(v[0], v[1]); q.y = pk2(v[2], v[3]);
                q.z = pk2(v[4], v[5]); q.w = pk2(v[6], v[7]);
                int kh = 2 * w + khl;
                *reinterpret_cast<uint4*>(&hbuf[((kh * 2 + nb) * 64 + lane) * 8]) = q;
            }
        }
    };

    // mm2 (out^T = W2^T h^T) -> kreg ; weights from regs
    auto do_mm2 = [&]() {
        f32x4 bv = *(const f32x4*)&b2b[16 * w + 4 * g];
        #pragma unroll
        for (int nb = 0; nb < 2; ++nb) kreg[nb] = bv;
        #pragma unroll
        for (int kh = 0; kh < 16; ++kh) {
            bf16x8 Bf[2];
            #pragma unroll
            for (int nb = 0; nb < 2; ++nb)
                Bf[nb] = *(const bf16x8*)&hbuf[((kh * 2 + nb) * 64 + lane) * 8];
            #pragma unroll
            for (int nb = 0; nb < 2; ++nb)
                kreg[nb] = __builtin_amdgcn_mfma_f32_16x16x32_bf16(W2r[kh], Bf[nb], kreg[nb], 0, 0, 0);
        }
    };

    auto f_eval = [&](float c) {
        build_xin(c);
        __syncthreads();
        do_mm1_ln();
        __syncthreads();
        do_mm2();
    };

    // regularization from kreg (= f(x) at current state)
    auto do_reg = [&]() {
        float amax[2] = {0, 0};
        #pragma unroll
        for (int nb = 0; nb < 2; ++nb)
            #pragma unroll
            for (int r = 0; r < 4; ++r)
                amax[nb] = fmaxf(amax[nb], fabsf(kreg[nb][r]));
        #pragma unroll
        for (int nb = 0; nb < 2; ++nb) {
            amax[nb] = fmaxf(amax[nb], __shfl_xor(amax[nb], 16));
            amax[nb] = fmaxf(amax[nb], __shfl_xor(amax[nb], 32));
        }
        if (lane < 16) {
            #pragma unroll
            for (int nb = 0; nb < 2; ++nb) rmx[(w * 2 + nb) * 16 + l15] = amax[nb];
        }
        __syncthreads();
        float rmax_[2];
        #pragma unroll
        for (int nb = 0; nb < 2; ++nb) {
            float m = rmx[(0 * 2 + nb) * 16 + l15];
            #pragma unroll
            for (int ww = 1; ww < 8; ++ww) m = fmaxf(m, rmx[(ww * 2 + nb) * 16 + l15]);
            rmax_[nb] = m;
        }
        float se[2] = {0, 0}, sa[2] = {0, 0};
        #pragma unroll
        for (int nb = 0; nb < 2; ++nb)
            #pragma unroll
            for (int r = 0; r < 4; ++r) {
                float a = fabsf(kreg[nb][r]);
                float e = __expf(a - rmax_[nb]);
                se[nb] += e; sa[nb] = fmaf(a, e, sa[nb]);
            }
        #pragma unroll
        for (int nb = 0; nb < 2; ++nb) {
            se[nb] += __shfl_xor(se[nb], 16); se[nb] += __shfl_xor(se[nb], 32);
            sa[nb] += __shfl_xor(sa[nb], 16); sa[nb] += __shfl_xor(sa[nb], 32);
        }
        if (lane < 16) {
            #pragma unroll
            for (int nb = 0; nb < 2; ++nb)
                lnb[(w * 2 + nb) * 16 + l15] = make_float2(se[nb], sa[nb]);
        }
        __syncthreads();
        if (w == 0) {
            // lanes 0..31 cover rows 16*(g&1)+l15
            int nb = g & 1;
            float nse = 0.f, nsa = 0.f;
            #pragma unroll
            for (int ww = 0; ww < 8; ++ww) {
                float2 v = lnb[(ww * 2 + nb) * 16 + l15];
                nse += v.x; nsa += v.y;
            }
            float nrm = (lane < 32) ? (nsa / nse) : 0.0f;
            #pragma unroll
            for (int m = 1; m < 64; m <<= 1) nrm += __shfl_xor(nrm, m);
            if (lane == 0) regtot += nrm;
        }
        __syncthreads();
    };

    for (int s = 0; s < 20; ++s) {
        f_eval(0.0f);                                   // k1 = f(x_s)
        if (s >= 12 && (s & 1) == 0) do_reg();          // x_s is reg state for s=12,14,16,18
        #pragma unroll
        for (int nb = 0; nb < 2; ++nb) acck[nb] = kreg[nb];
        f_eval(0.5f * DT_F);
        #pragma unroll
        for (int nb = 0; nb < 2; ++nb) acck[nb] += kreg[nb] * 2.0f;
        f_eval(0.5f * DT_F);
        #pragma unroll
        for (int nb = 0; nb < 2; ++nb) acck[nb] += kreg[nb] * 2.0f;
        f_eval(DT_F);
        #pragma unroll
        for (int nb = 0; nb < 2; ++nb) {
            acck[nb] += kreg[nb];
            xreg[nb] += acck[nb] * (DT_F / 6.0f);
        }
    }
    // final regularization eval at x_20
    f_eval(0.0f);
    do_reg();

    #pragma unroll
    for (int nb = 0; nb < 2; ++nb) {
        int brow = row0 + 16 * nb + l15;
        int ucol = 16 * w + 4 * g;
        *(f32x4*)&out[brow * 128 + ucol] = xreg[nb];
    }
    if (t == 0) regPart[blockIdx.x] = regtot;
}

__global__ __launch_bounds__(64)
void finalize_reg(const float* __restrict__ regPart, float* __restrict__ outReg)
{
    int t = threadIdx.x;
    float s = 0.f;
    #pragma unroll
    for (int i = 0; i < 8; ++i) s += regPart[t + 64 * i];
    #pragma unroll
    for (int m = 1; m < 64; m <<= 1) s += __shfl_xor(s, m);
    if (t == 0) outReg[0] = s * (1.0f / (5.0f * 16384.0f));
}

extern "C" void kernel_launch(void* const* d_in, const int* in_sizes, int n_in,
                              void* d_out, int out_size, void* d_ws, size_t ws_size,
                              hipStream_t stream)
{
    (void)in_sizes; (void)n_in; (void)out_size; (void)ws_size;
    const float* x0    = (const float*)d_in[0];
    const float* W1    = (const float*)d_in[1];
    const float* b1    = (const float*)d_in[2];
    const float* gamma = (const float*)d_in[3];
    const float* beta  = (const float*)d_in[4];
    const float* W2    = (const float*)d_in[5];
    const float* b2    = (const float*)d_in[6];
    float* out = (float*)d_out;

    ushort_t* w1p = (ushort_t*)d_ws;                       // 128 KB
    ushort_t* w2p = w1p + 65536;                           // 128 KB
    float* regPart = (float*)((char*)d_ws + 262144);       // 2 KB

    pack_weights<<<64, 256, 0, stream>>>(W1, W2, w1p, w2p);
    node_ode<<<512, 512, 50688, stream>>>(x0, gamma, beta, b1, b2, w1p, w2p, out, regPart);
    finalize_reg<<<1, 64, 0, stream>>>(regPart, out + 2097152);
}